// Round 16
// baseline (46.751 us; speedup 1.0000x reference)
//
#include <hip/hip_runtime.h>
#include <hip/hip_bf16.h>
#include <math.h>

#define DD 128
#define CC 100
#define NPAD 112          // 7 tiles of 16
#define NT 7
#define MARGIN_F 0.5f
#define EPS_F 1e-6f
#define RW 16             // rows per wave per chunk
#define CH 4              // chunks per wave
#define NWAVE 8           // waves per block
#define NTHR (NWAVE * 64) // 512 threads
#define BROWS 512         // rows per block = 8 waves * 16 rows * 4 chunks
#define NFRAG (NT * 4)    // 28 B-fragments

typedef __attribute__((ext_vector_type(8))) short bf16x8;
typedef __attribute__((ext_vector_type(4))) float f32x4;

__device__ __forceinline__ float fsqrt_f(float x) { return __builtin_amdgcn_sqrtf(x); }
__device__ __forceinline__ float frcp_f(float x)  { return __builtin_amdgcn_rcpf(x); }

__device__ __forceinline__ short f2bf(float x) {
    __hip_bfloat16 h = __float2bfloat16(x);
    return *reinterpret_cast<short*>(&h);
}

// prep: block j normalizes prototype j, emits cj[j] and B-fragment-major
// bf16 slices. j>=100: zero frags, cj=1e9 (pad kills hinge via min-trick).
// Block 0 initializes out to -MARGIN/(C-1) (label-column compensation).
// R9/R14: fusing this into main regressed (+8us/+4.3us) — keep two kernels.
__global__ void prep_kernel(const float* __restrict__ p,
                            float* __restrict__ cj,
                            bf16x8* __restrict__ pnb,
                            float* __restrict__ out) {
    int j = blockIdx.x, tid = threadIdx.x;
    if (j == 0 && tid == 0) out[0] = -MARGIN_F / (float)(CC - 1);

    float inv = 0.0f;
    if (j < CC) {
        float a = p[j * DD + tid];
        float b = p[j * DD + tid + 64];
        float ss = a * a + b * b;
        float s1 = a + b;
#pragma unroll
        for (int off = 1; off < 64; off <<= 1) {
            ss += __shfl_xor(ss, off);
            s1 += __shfl_xor(s1, off);
        }
        inv = 1.0f / fmaxf(sqrtf(ss), 1e-12f);
        if (tid == 0) cj[j] = ss * inv * inv - 2.0f * EPS_F * (s1 * inv);
    } else {
        if (tid == 0) cj[j] = 1e9f;
    }

    if (tid < 16) {
        int kk = tid >> 2, g = tid & 3;
        int frag = (j >> 4) * 4 + kk;
        int lane = g * 16 + (j & 15);
        bf16x8 o;
        if (j < CC) {
            const float* row = p + j * DD + kk * 32 + g * 8;
#pragma unroll
            for (int q = 0; q < 8; ++q) o[q] = f2bf(row[q] * inv);
        } else {
#pragma unroll
            for (int q = 0; q < 8; ++q) o[q] = 0;
        }
        pnb[frag * 64 + lane] = o;
    }
}

// main: occupancy probe — 8 waves/block x 4 chunks (vs R12's 4 waves x 8
// chunks). Same BROWS=512, same grid 512, same per-block fixed costs, same
// loop body; waves/SIMD doubles 2 -> 4 (if VGPR <= 128; no launch_bounds
// clamp per R4's spill catastrophe).
// Regressed probes (do not reapply): s_setprio (R10 +1.8us), depth-2
// register prefetch (R13 +1.9us), fused prep (R9 +8us / R14 +4.3us),
// launch_bounds min-waves (R4).
// d_pos via 4-MFMA gather (bitwise-equal to label column); hinge min-trick:
// sum relu(hb-dist) = 7*hb - sum min(dist,hb); pad cols contribute 0.
template <bool TAIL>
__global__ __launch_bounds__(NTHR) void proto_main_kernel(
        const float* __restrict__ feat,
        const bf16x8* __restrict__ pnb,
        const float* __restrict__ cj,
        const int* __restrict__ labels,
        float* __restrict__ out,
        int Bn, float scale) {
    const int tid = threadIdx.x;
    const int lane = tid & 63;
    const int w = tid >> 6;              // 0..7
    const int g = lane >> 4, m = lane & 15;
    const long blkbase = (long)blockIdx.x * BROWS;

    __shared__ bf16x8 pnl[NFRAG * 64];   // 28 KB
    __shared__ float cjs[NPAD];          // 448 B
    __shared__ float red[NWAVE];

    // loop-invariant: my 7 columns' cj
    float cjr[NT];
#pragma unroll
    for (int t = 0; t < NT; ++t) cjr[t] = cj[t * 16 + m];

    // issue chunk-0 feature+label loads FIRST (oldest on vmcnt; they land
    // under the LDS staging below)
    float4 va[8];
    int lab;
    {
        long row = blkbase + w * RW + m;
        long rs = (!TAIL || row < Bn) ? row : (long)(Bn - 1);
        lab = labels[rs];
        const float4* fp = (const float4*)(feat + rs * DD);
#pragma unroll
        for (int kk = 0; kk < 4; ++kk) {
            va[kk * 2]     = fp[kk * 8 + g * 2];
            va[kk * 2 + 1] = fp[kk * 8 + g * 2 + 1];
        }
    }

    // stage B fragments + cj table into LDS (once per block; 1792 entries)
#pragma unroll
    for (int i = 0; i < 4; ++i) {
        int idx = i * NTHR + tid;
        if (idx < NFRAG * 64) pnl[idx] = pnb[idx];
    }
    if (tid < NPAD) cjs[tid] = cj[tid];
    __syncthreads();   // drains staging (and chunk-0 loads with it)

    float hsum = 0.f;

#pragma unroll 1
    for (int c = 0; c < CH; ++c) {
        int labc = lab;

        // row-stat sums from raw floats (uses va of chunk c)
        float ss = 0.f, s1 = 0.f;
#pragma unroll
        for (int q = 0; q < 8; ++q) {
            float4 v = va[q];
            ss += v.x * v.x + v.y * v.y + v.z * v.z + v.w * v.w;
            s1 += v.x + v.y + v.z + v.w;
        }

        // raw floats -> bf16 A fragments (frees va for the prefetch)
        bf16x8 afr[4];
#pragma unroll
        for (int kk = 0; kk < 4; ++kk) {
            float4 a = va[kk * 2], b = va[kk * 2 + 1];
            union { bf16x8 v; __hip_bfloat162 h[4]; } u;
            u.h[0] = __float22bfloat162_rn(make_float2(a.x, a.y));
            u.h[1] = __float22bfloat162_rn(make_float2(a.z, a.w));
            u.h[2] = __float22bfloat162_rn(make_float2(b.x, b.y));
            u.h[3] = __float22bfloat162_rn(make_float2(b.z, b.w));
            afr[kk] = u.v;
        }

        // depth-1 prefetch: next chunk's label + features (ONLY vmcnt ops
        // in the loop; issued early to lengthen the latency shadow)
        if (c + 1 < CH) {
            long nrow = blkbase + (c + 1) * (NWAVE * RW) + w * RW + m;
            long nrs = (!TAIL || nrow < Bn) ? nrow : (long)(Bn - 1);
            lab = labels[nrs];
            const float4* fp = (const float4*)(feat + nrs * DD);
#pragma unroll
            for (int kk = 0; kk < 4; ++kk) {
                va[kk * 2]     = fp[kk * 8 + g * 2];
                va[kk * 2 + 1] = fp[kk * 8 + g * 2 + 1];
            }
        }

        // finish row stats (register/LDS-only from here to end of chunk)
        ss += __shfl_xor(ss, 16); ss += __shfl_xor(ss, 32);
        s1 += __shfl_xor(s1, 16); s1 += __shfl_xor(s1, 32);
        float inv = frcp_f(fmaxf(fsqrt_f(ss), 1e-12f));
        float cf = ss * inv * inv + 2.f * EPS_F * (s1 * inv)
                 + (float)DD * (EPS_F * EPS_F);
        float m2i = -2.f * inv;

        // per-row stats for my output rows q=g*4+r (held by lane q)
        float cf_r[4], m2i_r[4];
        int lab_r[4];
#pragma unroll
        for (int r = 0; r < 4; ++r) {
            int addr = (g * 4 + r) << 2;
            cf_r[r]  = __int_as_float(__builtin_amdgcn_ds_bpermute(addr, __float_as_int(cf)));
            m2i_r[r] = __int_as_float(__builtin_amdgcn_ds_bpermute(addr, __float_as_int(m2i)));
            lab_r[r] = __builtin_amdgcn_ds_bpermute(addr, labc);
        }
        // cj of each row's label prototype
        float cjl_r[4];
#pragma unroll
        for (int r = 0; r < 4; ++r) cjl_r[r] = cjs[lab_r[r]];

        // d_pos dots via gathered-B MFMA: col q of B = proto label[row q]
        f32x4 accpos = (f32x4)0.f;
        {
            int lanehi = lane & 48;
            int fbase = (labc >> 4) << 2;
            int lsub  = lanehi + (labc & 15);
#pragma unroll
            for (int kk = 0; kk < 4; ++kk) {
                bf16x8 bp = pnl[(fbase + kk) * 64 + lsub];
                accpos = __builtin_amdgcn_mfma_f32_16x16x32_bf16(
                    afr[kk], bp, accpos, 0, 0, 0);
            }
        }
        // diagonal D[q][q]: holder lane = (q>>2)*16+q holds it in reg q&3
        float a01 = (lane & 1) ? accpos[1] : accpos[0];
        float a23 = (lane & 1) ? accpos[3] : accpos[2];
        float vsrc = (lane & 2) ? a23 : a01;
        float hb[4];
        {
            int hl = (lane >> 4) * 20;   // holder lane for q=g*4+r is 20g+r
#pragma unroll
            for (int r = 0; r < 4; ++r) {
                float dotp = __int_as_float(
                    __builtin_amdgcn_ds_bpermute((hl + r) << 2, __float_as_int(vsrc)));
                float d2p = fmaf(dotp, m2i_r[r], cf_r[r]) + cjl_r[r];
                float dpd = fsqrt_f(fmaxf(d2p, 1e-12f));
                if (TAIL) {
                    long rr = blkbase + c * (NWAVE * RW) + w * RW + g * 4 + r;
                    hb[r] = (rr < (long)Bn) ? (dpd + MARGIN_F) : 0.f;
                } else {
                    hb[r] = dpd + MARGIN_F;
                }
            }
        }

        // main MFMA: [16 rows] x [112 cols]; B operands via ds_read_b128
        f32x4 acc[NT];
#pragma unroll
        for (int t = 0; t < NT; ++t) acc[t] = (f32x4)0.f;
#pragma unroll
        for (int t = 0; t < NT; ++t) {
            bf16x8 bfr[4];
#pragma unroll
            for (int kk = 0; kk < 4; ++kk) bfr[kk] = pnl[(t * 4 + kk) * 64 + lane];
#pragma unroll
            for (int kk = 0; kk < 4; ++kk)
                acc[t] = __builtin_amdgcn_mfma_f32_16x16x32_bf16(
                    afr[kk], bfr[kk], acc[t], 0, 0, 0);
        }

        // epilogue: 5 instr/elem {fma, add, sqrt, min, add}
        float ms0 = 0.f, ms1 = 0.f, ms2 = 0.f, ms3 = 0.f;
#pragma unroll
        for (int t = 0; t < NT; ++t) {
            float e0 = fmaf(acc[t][0], m2i_r[0], cf_r[0]);
            float e1 = fmaf(acc[t][1], m2i_r[1], cf_r[1]);
            float e2 = fmaf(acc[t][2], m2i_r[2], cf_r[2]);
            float e3 = fmaf(acc[t][3], m2i_r[3], cf_r[3]);
            ms0 += fminf(fsqrt_f(e0 + cjr[t]), hb[0]);
            ms1 += fminf(fsqrt_f(e1 + cjr[t]), hb[1]);
            ms2 += fminf(fsqrt_f(e2 + cjr[t]), hb[2]);
            ms3 += fminf(fsqrt_f(e3 + cjr[t]), hb[3]);
        }
        hsum += fmaf((float)NT, hb[0], -ms0);
        hsum += fmaf((float)NT, hb[1], -ms1);
        hsum += fmaf((float)NT, hb[2], -ms2);
        hsum += fmaf((float)NT, hb[3], -ms3);
    }

    // wave reduce + 1 barrier + 1 atomic per block
#pragma unroll
    for (int off = 32; off > 0; off >>= 1) hsum += __shfl_xor(hsum, off);
    if (lane == 0) red[w] = hsum;
    __syncthreads();
    if (tid == 0) {
        float total = 0.f;
#pragma unroll
        for (int i = 0; i < NWAVE; ++i) total += red[i];
        atomicAdd(out, total * scale);
    }
}

extern "C" void kernel_launch(void* const* d_in, const int* in_sizes, int n_in,
                              void* d_out, int out_size, void* d_ws, size_t ws_size,
                              hipStream_t stream) {
    const float* feat   = (const float*)d_in[0];
    const float* prot   = (const float*)d_in[1];
    const int*   labels = (const int*)d_in[2];
    float* out = (float*)d_out;
    int Bn = in_sizes[0] / DD;

    bf16x8* pnb = (bf16x8*)d_ws;                       // 28*64*16B = 28672 B
    float* cjw  = (float*)((char*)d_ws + 28 * 64 * 16);

    prep_kernel<<<NPAD, 64, 0, stream>>>(prot, cjw, pnb, out);

    int blocks = (Bn + BROWS - 1) / BROWS;
    float scale = 1.0f / ((float)Bn * (float)(CC - 1));
    if (Bn % BROWS == 0)
        proto_main_kernel<false><<<blocks, NTHR, 0, stream>>>(feat, pnb, cjw, labels, out, Bn, scale);
    else
        proto_main_kernel<true><<<blocks, NTHR, 0, stream>>>(feat, pnb, cjw, labels, out, Bn, scale);
}

// Round 17
// 38.387 us; speedup vs baseline: 1.2179x; 1.2179x over previous
//
#include <hip/hip_runtime.h>
#include <hip/hip_bf16.h>
#include <math.h>

#define DD 128
#define CC 100
#define NPAD 112          // 7 tiles of 16
#define NT 7
#define MARGIN_F 0.5f
#define EPS_F 1e-6f
#define RW 16             // rows per wave per chunk
#define CH 8              // chunks per wave (software pipeline depth)
#define BROWS 512         // rows per block = 4 waves * RW * CH -> 512 blocks = 2/CU exact
#define NFRAG (NT * 4)    // 28 B-fragments

typedef __attribute__((ext_vector_type(8))) short bf16x8;
typedef __attribute__((ext_vector_type(4))) float f32x4;

__device__ __forceinline__ float fsqrt_f(float x) { return __builtin_amdgcn_sqrtf(x); }
__device__ __forceinline__ float frcp_f(float x)  { return __builtin_amdgcn_rcpf(x); }

__device__ __forceinline__ short f2bf(float x) {
    __hip_bfloat16 h = __float2bfloat16(x);
    return *reinterpret_cast<short*>(&h);
}

// prep: block j normalizes prototype j, emits cj[j] and B-fragment-major
// bf16 slices. j>=100: zero frags, cj=1e9 (pad kills hinge via min-trick).
// Block 0 initializes out to -MARGIN/(C-1): the label column of the main
// MFMA contributes exactly MARGIN per row (the d_pos gather-MFMA is
// bitwise-identical to it), so one global subtraction compensates exactly.
// R9/R14: fusing this into main regressed (+8us/+4.3us) — keep two kernels.
__global__ void prep_kernel(const float* __restrict__ p,
                            float* __restrict__ cj,
                            bf16x8* __restrict__ pnb,
                            float* __restrict__ out) {
    int j = blockIdx.x, tid = threadIdx.x;
    if (j == 0 && tid == 0) out[0] = -MARGIN_F / (float)(CC - 1);

    float inv = 0.0f;
    if (j < CC) {
        float a = p[j * DD + tid];
        float b = p[j * DD + tid + 64];
        float ss = a * a + b * b;
        float s1 = a + b;
#pragma unroll
        for (int off = 1; off < 64; off <<= 1) {
            ss += __shfl_xor(ss, off);
            s1 += __shfl_xor(s1, off);
        }
        inv = 1.0f / fmaxf(sqrtf(ss), 1e-12f);
        if (tid == 0) cj[j] = ss * inv * inv - 2.0f * EPS_F * (s1 * inv);
    } else {
        if (tid == 0) cj[j] = 1e9f;
    }

    if (tid < 16) {
        int kk = tid >> 2, g = tid & 3;
        int frag = (j >> 4) * 4 + kk;
        int lane = g * 16 + (j & 15);
        bf16x8 o;
        if (j < CC) {
            const float* row = p + j * DD + kk * 32 + g * 8;
#pragma unroll
            for (int q = 0; q < 8; ++q) o[q] = f2bf(row[q] * inv);
        } else {
#pragma unroll
            for (int q = 0; q < 8; ++q) o[q] = 0;
        }
        pnb[frag * 64 + lane] = o;
    }
}

// main: 4 waves/block, 16 rows/wave/chunk, 8 chunks software-pipelined.
// Twice-verified optimum (R12: 38.30us, R15: 38.60us).
// BROWS=512 -> grid 512 = exactly 2 blocks/CU: no residency tail, minimal
// per-block fixed costs. vmcnt carries ONLY the 9 prefetch loads per chunk;
// B fragments live in LDS (lgkmcnt domain).
// Probes that REGRESSED (do not reapply): s_setprio (R10 +1.8us), depth-2
// register prefetch (R13 +1.9us), fused prototype prep (R9 +8us / R14
// +4.3us), launch_bounds min-waves (R4: VGPR=64 spill catastrophe),
// 8 waves/block occupancy boost (R16 +8.5us), 16-rows-per-thread blocks
// at 1024 grid (R11 ~+2us).
// TAIL=false (Bn % BROWS == 0): no row clamps or valid masks.
// d_pos via 4-MFMA gather (bitwise-equal to the label column); hinge via
// min-trick: sum relu(hb-dist) = 7*hb - sum min(dist, hb) per lane; pad
// cols (cj=1e9 -> dist~3e4 -> min=hb) contribute exactly 0.
template <bool TAIL>
__global__ __launch_bounds__(256) void proto_main_kernel(
        const float* __restrict__ feat,
        const bf16x8* __restrict__ pnb,
        const float* __restrict__ cj,
        const int* __restrict__ labels,
        float* __restrict__ out,
        int Bn, float scale) {
    const int lane = threadIdx.x & 63;
    const int w = threadIdx.x >> 6;
    const int g = lane >> 4, m = lane & 15;
    const long blkbase = (long)blockIdx.x * BROWS;

    __shared__ bf16x8 pnl[NFRAG * 64];   // 28 KB
    __shared__ float cjs[NPAD];          // 448 B
    __shared__ float red[4];

    // loop-invariant: my 7 columns' cj
    float cjr[NT];
#pragma unroll
    for (int t = 0; t < NT; ++t) cjr[t] = cj[t * 16 + m];

    // issue chunk-0 feature+label loads FIRST (oldest on vmcnt; they land
    // under the LDS staging below)
    float4 va[8];
    int lab;
    {
        long row = blkbase + w * RW + m;
        long rs = (!TAIL || row < Bn) ? row : (long)(Bn - 1);
        lab = labels[rs];
        const float4* fp = (const float4*)(feat + rs * DD);
#pragma unroll
        for (int kk = 0; kk < 4; ++kk) {
            va[kk * 2]     = fp[kk * 8 + g * 2];
            va[kk * 2 + 1] = fp[kk * 8 + g * 2 + 1];
        }
    }

    // stage B fragments + cj table into LDS (once per block)
#pragma unroll
    for (int i = 0; i < NFRAG * 64 / 256; ++i)
        pnl[i * 256 + threadIdx.x] = pnb[i * 256 + threadIdx.x];
    if (threadIdx.x < NPAD) cjs[threadIdx.x] = cj[threadIdx.x];
    __syncthreads();   // drains staging (and chunk-0 loads with it)

    float hsum = 0.f;

#pragma unroll 1
    for (int c = 0; c < CH; ++c) {
        int labc = lab;

        // row-stat sums from raw floats (uses va of chunk c)
        float ss = 0.f, s1 = 0.f;
#pragma unroll
        for (int q = 0; q < 8; ++q) {
            float4 v = va[q];
            ss += v.x * v.x + v.y * v.y + v.z * v.z + v.w * v.w;
            s1 += v.x + v.y + v.z + v.w;
        }

        // raw floats -> bf16 A fragments (frees va for the prefetch)
        bf16x8 afr[4];
#pragma unroll
        for (int kk = 0; kk < 4; ++kk) {
            float4 a = va[kk * 2], b = va[kk * 2 + 1];
            union { bf16x8 v; __hip_bfloat162 h[4]; } u;
            u.h[0] = __float22bfloat162_rn(make_float2(a.x, a.y));
            u.h[1] = __float22bfloat162_rn(make_float2(a.z, a.w));
            u.h[2] = __float22bfloat162_rn(make_float2(b.x, b.y));
            u.h[3] = __float22bfloat162_rn(make_float2(b.z, b.w));
            afr[kk] = u.v;
        }

        // depth-1 prefetch: next chunk's label + features ASAP (ONLY vmcnt
        // ops in the loop; issued before the shuffle/sqrt chain to lengthen
        // the latency shadow)
        if (c + 1 < CH) {
            long nrow = blkbase + (c + 1) * 64 + w * RW + m;
            long nrs = (!TAIL || nrow < Bn) ? nrow : (long)(Bn - 1);
            lab = labels[nrs];
            const float4* fp = (const float4*)(feat + nrs * DD);
#pragma unroll
            for (int kk = 0; kk < 4; ++kk) {
                va[kk * 2]     = fp[kk * 8 + g * 2];
                va[kk * 2 + 1] = fp[kk * 8 + g * 2 + 1];
            }
        }

        // finish row stats (register/LDS-only from here to end of chunk)
        ss += __shfl_xor(ss, 16); ss += __shfl_xor(ss, 32);
        s1 += __shfl_xor(s1, 16); s1 += __shfl_xor(s1, 32);
        float inv = frcp_f(fmaxf(fsqrt_f(ss), 1e-12f));
        float cf = ss * inv * inv + 2.f * EPS_F * (s1 * inv)
                 + (float)DD * (EPS_F * EPS_F);
        float m2i = -2.f * inv;

        // per-row stats for my output rows q=g*4+r (held by lane q)
        float cf_r[4], m2i_r[4];
        int lab_r[4];
#pragma unroll
        for (int r = 0; r < 4; ++r) {
            int addr = (g * 4 + r) << 2;
            cf_r[r]  = __int_as_float(__builtin_amdgcn_ds_bpermute(addr, __float_as_int(cf)));
            m2i_r[r] = __int_as_float(__builtin_amdgcn_ds_bpermute(addr, __float_as_int(m2i)));
            lab_r[r] = __builtin_amdgcn_ds_bpermute(addr, labc);
        }
        // cj of each row's label prototype
        float cjl_r[4];
#pragma unroll
        for (int r = 0; r < 4; ++r) cjl_r[r] = cjs[lab_r[r]];

        // d_pos dots via gathered-B MFMA: col q of B = proto label[row q]
        f32x4 accpos = (f32x4)0.f;
        {
            int lanehi = lane & 48;
            int fbase = (labc >> 4) << 2;
            int lsub  = lanehi + (labc & 15);
#pragma unroll
            for (int kk = 0; kk < 4; ++kk) {
                bf16x8 bp = pnl[(fbase + kk) * 64 + lsub];
                accpos = __builtin_amdgcn_mfma_f32_16x16x32_bf16(
                    afr[kk], bp, accpos, 0, 0, 0);
            }
        }
        // diagonal D[q][q]: holder lane = (q>>2)*16+q holds it in reg q&3
        float a01 = (lane & 1) ? accpos[1] : accpos[0];
        float a23 = (lane & 1) ? accpos[3] : accpos[2];
        float vsrc = (lane & 2) ? a23 : a01;
        float hb[4];
        {
            int hl = (lane >> 4) * 20;   // holder lane for q=g*4+r is 20g+r
#pragma unroll
            for (int r = 0; r < 4; ++r) {
                float dotp = __int_as_float(
                    __builtin_amdgcn_ds_bpermute((hl + r) << 2, __float_as_int(vsrc)));
                float d2p = fmaf(dotp, m2i_r[r], cf_r[r]) + cjl_r[r];
                float dpd = fsqrt_f(fmaxf(d2p, 1e-12f));
                if (TAIL) {
                    long rr = blkbase + c * 64 + w * RW + g * 4 + r;
                    hb[r] = (rr < (long)Bn) ? (dpd + MARGIN_F) : 0.f;
                } else {
                    hb[r] = dpd + MARGIN_F;
                }
            }
        }

        // main MFMA: [16 rows] x [112 cols]; B operands via ds_read_b128
        f32x4 acc[NT];
#pragma unroll
        for (int t = 0; t < NT; ++t) acc[t] = (f32x4)0.f;
#pragma unroll
        for (int t = 0; t < NT; ++t) {
            bf16x8 bfr[4];
#pragma unroll
            for (int kk = 0; kk < 4; ++kk) bfr[kk] = pnl[(t * 4 + kk) * 64 + lane];
#pragma unroll
            for (int kk = 0; kk < 4; ++kk)
                acc[t] = __builtin_amdgcn_mfma_f32_16x16x32_bf16(
                    afr[kk], bfr[kk], acc[t], 0, 0, 0);
        }

        // epilogue: 5 instr/elem {fma, add, sqrt, min, add}
        float ms0 = 0.f, ms1 = 0.f, ms2 = 0.f, ms3 = 0.f;
#pragma unroll
        for (int t = 0; t < NT; ++t) {
            float e0 = fmaf(acc[t][0], m2i_r[0], cf_r[0]);
            float e1 = fmaf(acc[t][1], m2i_r[1], cf_r[1]);
            float e2 = fmaf(acc[t][2], m2i_r[2], cf_r[2]);
            float e3 = fmaf(acc[t][3], m2i_r[3], cf_r[3]);
            ms0 += fminf(fsqrt_f(e0 + cjr[t]), hb[0]);
            ms1 += fminf(fsqrt_f(e1 + cjr[t]), hb[1]);
            ms2 += fminf(fsqrt_f(e2 + cjr[t]), hb[2]);
            ms3 += fminf(fsqrt_f(e3 + cjr[t]), hb[3]);
        }
        hsum += fmaf((float)NT, hb[0], -ms0);
        hsum += fmaf((float)NT, hb[1], -ms1);
        hsum += fmaf((float)NT, hb[2], -ms2);
        hsum += fmaf((float)NT, hb[3], -ms3);
    }

    // wave reduce + 1 barrier + 1 atomic per block
#pragma unroll
    for (int off = 32; off > 0; off >>= 1) hsum += __shfl_xor(hsum, off);
    if (lane == 0) red[w] = hsum;
    __syncthreads();
    if (threadIdx.x == 0)
        atomicAdd(out, (red[0] + red[1] + red[2] + red[3]) * scale);
}

extern "C" void kernel_launch(void* const* d_in, const int* in_sizes, int n_in,
                              void* d_out, int out_size, void* d_ws, size_t ws_size,
                              hipStream_t stream) {
    const float* feat   = (const float*)d_in[0];
    const float* prot   = (const float*)d_in[1];
    const int*   labels = (const int*)d_in[2];
    float* out = (float*)d_out;
    int Bn = in_sizes[0] / DD;

    bf16x8* pnb = (bf16x8*)d_ws;                       // 28*64*16B = 28672 B
    float* cjw  = (float*)((char*)d_ws + 28 * 64 * 16);

    prep_kernel<<<NPAD, 64, 0, stream>>>(prot, cjw, pnb, out);

    int blocks = (Bn + BROWS - 1) / BROWS;
    float scale = 1.0f / ((float)Bn * (float)(CC - 1));
    if (Bn % BROWS == 0)
        proto_main_kernel<false><<<blocks, 256, 0, stream>>>(feat, pnb, cjw, labels, out, Bn, scale);
    else
        proto_main_kernel<true><<<blocks, 256, 0, stream>>>(feat, pnb, cjw, labels, out, Bn, scale);
}